// Round 3
// baseline (112.703 us; speedup 1.0000x reference)
//
#include <hip/hip_runtime.h>
#include <hip/hip_bf16.h>

#define HW    3136
#define HH    56
#define NCIN  256
#define MOUT  96    // 16 (x1) + 16 (x2) + 64 (x3)
#define KK    49

// ws: xcat [B][96][HW] @ 0
#define OFF_XCAT  0

__device__ __forceinline__ int refl(int p) {
    return p < 0 ? -p : (p > 55 ? 110 - p : p);
}

// ---------------- fused 1x1 convs: xcat[b][96][hw] ----------------
// 256 thr = 4 og-groups(24 o) x 64 px-lanes; block covers 64 px.
__global__ __launch_bounds__(256) void kconv(
    const float* __restrict__ x,
    const float* __restrict__ w1, const float* __restrict__ b1,
    const float* __restrict__ w2, const float* __restrict__ b2,
    const float* __restrict__ w3, const float* __restrict__ b3,
    float* __restrict__ xcat)
{
    __shared__ float wl[64][100];   // [c][o], stride 100 keeps float4 align
    __shared__ float xl[64][64];    // [c][px]
    const int tid = threadIdx.x;
    const int b   = blockIdx.x / 49;
    const int hw0 = (blockIdx.x % 49) * 64;
    const int l   = tid & 63;
    const int og  = tid >> 6;       // 0..3
    const int ob  = og * 24;

    float acc[24];
#pragma unroll
    for (int oo = 0; oo < 24; ++oo) {
        int o = ob + oo;
        acc[oo] = (o < 16) ? b1[o] : (o < 32) ? b2[o - 16] : b3[o - 32];
    }

    const float* xb = x + (size_t)b * NCIN * HW + hw0;

    for (int cc = 0; cc < 4; ++cc) {
        __syncthreads();
        // stage weights: wl[c][o] = W[o][cc*64+c], read direct from w1/w2/w3
#pragma unroll
        for (int t = 0; t < 24; ++t) {
            int idx = t * 256 + tid;           // 0..6143
            int o = idx >> 6, c = idx & 63;    // o wave-uniform
            const float* src = (o < 16) ? w1 + o * 256
                             : (o < 32) ? w2 + (o - 16) * 256
                                        : w3 + (o - 32) * 256;
            wl[c][o] = src[cc * 64 + c];
        }
        // stage x chunk (coalesced 64-px rows)
#pragma unroll
        for (int i = 0; i < 16; ++i) {
            int c = i * 4 + og;
            xl[c][l] = xb[(size_t)(cc * 64 + c) * HW + l];
        }
        __syncthreads();
#pragma unroll 2
        for (int c = 0; c < 64; ++c) {
            float xv = xl[c][l];
            float wv[24];
#pragma unroll
            for (int q = 0; q < 6; ++q)
                *(float4*)&wv[q * 4] = *(const float4*)&wl[c][ob + q * 4];
#pragma unroll
            for (int oo = 0; oo < 24; ++oo)
                acc[oo] = fmaf(xv, wv[oo], acc[oo]);
        }
    }

    float* outp = xcat + (size_t)b * MOUT * HW + hw0;
#pragma unroll
    for (int oo = 0; oo < 24; ++oo)
        outp[(size_t)(ob + oo) * HW + l] = acc[oo];
}

// ---------------- fused t + aggregation ----------------
// 512 thr = 8 waves; block = 64 px. Phase 0: BN-fold tables into LDS.
// Phase 1: t[8] per px (8-wave tap split + LDS reduce).
// Phase 2: thread=(g,px): 49-tap aggregation, wv computed on the fly.
__global__ __launch_bounds__(512) void kfused(
    const float* __restrict__ xcat,
    const float* __restrict__ bn1g, const float* __restrict__ bn1b,
    const float* __restrict__ bn1m, const float* __restrict__ bn1v,
    const float* __restrict__ wcw1,
    const float* __restrict__ bn2g, const float* __restrict__ bn2b,
    const float* __restrict__ bn2m, const float* __restrict__ bn2v,
    const float* __restrict__ wcw2, const float* __restrict__ bcw2,
    float* __restrict__ out)
{
    __shared__ float s1l[800], sh1l[800];
    __shared__ float wc1tl[800][8];
    __shared__ float red[8][8][64];
    __shared__ float tl[8][64];
    __shared__ float b2fl[8];

    const int tid = threadIdx.x;
    const int w   = tid >> 6;
    const int l   = tid & 63;
    const int pxg = blockIdx.x * 64;     // 64 | HW, blocks never straddle b
    const int b   = pxg / HW;
    const int nb  = pxg - b * HW;
    const int n   = nb + l;
    const int y   = n / HH;
    const int xx  = n - y * HH;

    // ---- phase 0: BN-fold tables (cheap, per-block) ----
    for (int i = tid; i < 800; i += 512) {
        float s = bn1g[i] / sqrtf(bn1v[i] + 1e-5f);
        s1l[i]  = s;
        sh1l[i] = bn1b[i] - bn1m[i] * s;
    }
    for (int i = tid; i < 6400; i += 512) {
        int j = i >> 3, g = i & 7;
        float s2 = bn2g[g] / sqrtf(bn2v[g] + 1e-5f);
        wc1tl[j][g] = wcw1[g * 800 + j] * s2;
    }
    if (tid < 8) {
        float s2 = bn2g[tid] / sqrtf(bn2v[tid] + 1e-5f);
        b2fl[tid] = bn2b[tid] - bn2m[tid] * s2;
    }
    __syncthreads();

    // ---- phase 1: t ----
    const float* x1 = xcat + (size_t)b * MOUT * HW;
    const float* x2 = x1 + 16 * HW;

    float acc[8];
#pragma unroll
    for (int g = 0; g < 8; ++g) acc[g] = 0.f;

    const int u0 = (50 * w) >> 3;
    const int u1 = (50 * (w + 1)) >> 3;

#pragma unroll 1
    for (int u = u0; u < u1; ++u) {
        if (u == 0) {
#pragma unroll
            for (int r = 0; r < 16; ++r) {
                float v = x1[r * HW + n];
                v = fmaxf(fmaf(v, s1l[r], sh1l[r]), 0.f);
                float4 wa = *(const float4*)&wc1tl[r][0];
                float4 wb = *(const float4*)&wc1tl[r][4];
                acc[0] = fmaf(v, wa.x, acc[0]); acc[1] = fmaf(v, wa.y, acc[1]);
                acc[2] = fmaf(v, wa.z, acc[2]); acc[3] = fmaf(v, wa.w, acc[3]);
                acc[4] = fmaf(v, wb.x, acc[4]); acc[5] = fmaf(v, wb.y, acc[5]);
                acc[6] = fmaf(v, wb.z, acc[6]); acc[7] = fmaf(v, wb.w, acc[7]);
            }
        } else {
            const int kk = __builtin_amdgcn_readfirstlane(u - 1);
            const int i  = kk / 7;
            const int jj = kk - i * 7;
            int p = y + 2 * i - 6;
            int q = xx + 2 * jj - 6;
            bool z = (p < -2) | (p > 57) | (q < -2) | (q > 57);
            int off = refl(p) * HH + refl(q);
            const float* x2o = x2 + off;
#pragma unroll
            for (int r = 0; r < 16; ++r) {
                const int j = 16 + r * KK + kk;   // wave-uniform
                float v = z ? 0.f : x2o[(size_t)r * HW];
                v = fmaxf(fmaf(v, s1l[j], sh1l[j]), 0.f);
                float4 wa = *(const float4*)&wc1tl[j][0];
                float4 wb = *(const float4*)&wc1tl[j][4];
                acc[0] = fmaf(v, wa.x, acc[0]); acc[1] = fmaf(v, wa.y, acc[1]);
                acc[2] = fmaf(v, wa.z, acc[2]); acc[3] = fmaf(v, wa.w, acc[3]);
                acc[4] = fmaf(v, wb.x, acc[4]); acc[5] = fmaf(v, wb.y, acc[5]);
                acc[6] = fmaf(v, wb.z, acc[6]); acc[7] = fmaf(v, wb.w, acc[7]);
            }
        }
    }

#pragma unroll
    for (int g = 0; g < 8; ++g) red[w][g][l] = acc[g];
    __syncthreads();
    {
        const int g  = tid >> 6;
        const int px = tid & 63;
        float s = b2fl[g];
#pragma unroll
        for (int ww = 0; ww < 8; ++ww) s += red[ww][g][px];
        tl[g][px] = fmaxf(s, 0.f);
    }
    __syncthreads();

    // ---- phase 2: aggregation ----
    const int g = __builtin_amdgcn_readfirstlane(tid >> 6);
    float t[8];
#pragma unroll
    for (int e = 0; e < 8; ++e) t[e] = tl[e][l];

    const float* x3   = xcat + ((size_t)b * MOUT + 32 + g * 8) * HW;
    const float* wrow = wcw2 + (size_t)g * KK * 8;   // wave-uniform -> scalar
    const float* brow = bcw2 + (size_t)g * KK;

    float acc2[8];
#pragma unroll
    for (int s = 0; s < 8; ++s) acc2[s] = 0.f;

#pragma unroll 1
    for (int i = 0; i < 7; ++i) {
        int p  = y + 2 * i - 6;
        int py = refl(p);
#pragma unroll
        for (int jj = 0; jj < 7; ++jj) {
            int q  = xx + 2 * jj - 6;
            int px = refl(q);
            int off = py * HH + px;
            int k   = i * 7 + jj;
            float wv = brow[k];
#pragma unroll
            for (int e = 0; e < 8; ++e) wv = fmaf(t[e], wrow[k * 8 + e], wv);
#pragma unroll
            for (int s = 0; s < 8; ++s)
                acc2[s] = fmaf(x3[(size_t)s * HW + off], wv, acc2[s]);
        }
    }

    float* op = out + ((size_t)b * 64 + g * 8) * HW + n;
#pragma unroll
    for (int s = 0; s < 8; ++s) op[(size_t)s * HW] = acc2[s];
}

extern "C" void kernel_launch(void* const* d_in, const int* in_sizes, int n_in,
                              void* d_out, int out_size, void* d_ws, size_t ws_size,
                              hipStream_t stream) {
    const float* x    = (const float*)d_in[0];
    const float* w1   = (const float*)d_in[1];
    const float* b1   = (const float*)d_in[2];
    const float* w2   = (const float*)d_in[3];
    const float* b2   = (const float*)d_in[4];
    const float* w3   = (const float*)d_in[5];
    const float* b3   = (const float*)d_in[6];
    const float* bn1g = (const float*)d_in[7];
    const float* bn1b = (const float*)d_in[8];
    const float* bn1m = (const float*)d_in[9];
    const float* bn1v = (const float*)d_in[10];
    const float* wcw1 = (const float*)d_in[11];
    const float* bn2g = (const float*)d_in[12];
    const float* bn2b = (const float*)d_in[13];
    const float* bn2m = (const float*)d_in[14];
    const float* bn2v = (const float*)d_in[15];
    const float* wcw2 = (const float*)d_in[16];
    const float* bcw2 = (const float*)d_in[17];

    float* xcat = (float*)d_ws + OFF_XCAT;

    kconv<<<392, 256, 0, stream>>>(x, w1, b1, w2, b2, w3, b3, xcat);
    kfused<<<392, 512, 0, stream>>>(xcat, bn1g, bn1b, bn1m, bn1v, wcw1,
                                    bn2g, bn2b, bn2m, bn2v, wcw2, bcw2,
                                    (float*)d_out);
}

// Round 4
// 95.969 us; speedup vs baseline: 1.1744x; 1.1744x over previous
//
#include <hip/hip_runtime.h>
#include <hip/hip_bf16.h>

#define HW    3136
#define HH    56
#define NCIN  256
#define MOUT  96    // 16 (x1) + 16 (x2) + 64 (x3)
#define KK    49

// ---------------- ws layout (in floats) ----------------
// wT     : [256][96]   @ 0       (transposed concat weights)
// bcat   : [96]        @ 24576
// s1/sh1 : [800] each  @ 24672 / 25472
// wc1t   : [800][8]    @ 26272   (bn2-folded, transposed wcw1)
// b2f    : [8]         @ 32672
// xcat   : [B][96][HW] @ 32768
#define OFF_WT    0
#define OFF_BCAT  24576
#define OFF_S1    24672
#define OFF_SH1   25472
#define OFF_WC1T  26272
#define OFF_B2F   32672
#define OFF_XCAT  32768

__device__ __forceinline__ int refl(int p) {
    return p < 0 ? -p : (p > 55 ? 110 - p : p);
}

// ---------------- precompute / repack ----------------
__global__ __launch_bounds__(256) void kprep(
    const float* __restrict__ w1, const float* __restrict__ b1,
    const float* __restrict__ w2, const float* __restrict__ b2,
    const float* __restrict__ w3, const float* __restrict__ b3,
    const float* __restrict__ bn1g, const float* __restrict__ bn1b,
    const float* __restrict__ bn1m, const float* __restrict__ bn1v,
    const float* __restrict__ wcw1,
    const float* __restrict__ bn2g, const float* __restrict__ bn2b,
    const float* __restrict__ bn2m, const float* __restrict__ bn2v,
    float* __restrict__ ws)
{
    int idx = blockIdx.x * 256 + threadIdx.x;
    if (idx < 24576) {                    // wT[c][o] = W[o][c]
        int o = idx >> 8, c = idx & 255;
        float v = (o < 16) ? w1[o * 256 + c]
                : (o < 32) ? w2[(o - 16) * 256 + c]
                           : w3[(o - 32) * 256 + c];
        ws[OFF_WT + c * 96 + o] = v;
    }
    int i2 = idx - 24576;
    if (i2 >= 0 && i2 < 96) {
        float v = (i2 < 16) ? b1[i2] : (i2 < 32) ? b2[i2 - 16] : b3[i2 - 32];
        ws[OFF_BCAT + i2] = v;
    }
    int i3 = idx - 24672;
    if (i3 >= 0 && i3 < 800) {
        float s = bn1g[i3] / sqrtf(bn1v[i3] + 1e-5f);
        ws[OFF_S1 + i3]  = s;
        ws[OFF_SH1 + i3] = bn1b[i3] - bn1m[i3] * s;
    }
    int i4 = idx - 25472;
    if (i4 >= 0 && i4 < 6400) {
        int j = i4 >> 3, g = i4 & 7;
        float s2 = bn2g[g] / sqrtf(bn2v[g] + 1e-5f);
        ws[OFF_WC1T + i4] = wcw1[g * 800 + j] * s2;
    }
    int i5 = idx - 31872;
    if (i5 >= 0 && i5 < 8) {
        float s2 = bn2g[i5] / sqrtf(bn2v[i5] + 1e-5f);
        ws[OFF_B2F + i5] = bn2b[i5] - bn2m[i5] * s2;
    }
}

// ---------------- fused 1x1 convs: xcat[b][96][hw] ----------------
// 512 thr = 8 waves; block = 64 px; wave w owns out-ch [12w,12w+12).
// Weights via wave-uniform pointer -> scalar s_loads (SGPR operand FMA).
__global__ __launch_bounds__(512) void kconv(
    const float* __restrict__ x, const float* __restrict__ wT,
    const float* __restrict__ bcat, float* __restrict__ xcat)
{
    __shared__ float xl[64][64];
    const int tid = threadIdx.x;
    const int l   = tid & 63;
    const int wv  = __builtin_amdgcn_readfirstlane(tid >> 6);
    const int b   = blockIdx.x / 49;
    const int hw0 = (blockIdx.x % 49) * 64;
    const int ob  = wv * 12;

    float acc[12];
    const float* bc = bcat + ob;
#pragma unroll
    for (int i = 0; i < 12; ++i) acc[i] = bc[i];

    const float* xb = x + (size_t)b * NCIN * HW + hw0;

    for (int cc = 0; cc < 4; ++cc) {
        __syncthreads();
#pragma unroll
        for (int i = 0; i < 8; ++i)
            xl[i * 8 + wv][l] = xb[(size_t)(cc * 64 + i * 8 + wv) * HW + l];
        __syncthreads();

        const float* wp = wT + (cc * 64) * 96 + ob;
#pragma unroll 4
        for (int k = 0; k < 64; ++k) {
            float xv = xl[k][l];
            const float4* wq = (const float4*)(wp + k * 96);
            float4 A = wq[0], B = wq[1], C = wq[2];
            acc[0]  = fmaf(xv, A.x, acc[0]);  acc[1]  = fmaf(xv, A.y, acc[1]);
            acc[2]  = fmaf(xv, A.z, acc[2]);  acc[3]  = fmaf(xv, A.w, acc[3]);
            acc[4]  = fmaf(xv, B.x, acc[4]);  acc[5]  = fmaf(xv, B.y, acc[5]);
            acc[6]  = fmaf(xv, B.z, acc[6]);  acc[7]  = fmaf(xv, B.w, acc[7]);
            acc[8]  = fmaf(xv, C.x, acc[8]);  acc[9]  = fmaf(xv, C.y, acc[9]);
            acc[10] = fmaf(xv, C.z, acc[10]); acc[11] = fmaf(xv, C.w, acc[11]);
        }
    }

    float* outp = xcat + (size_t)b * MOUT * HW + hw0;
#pragma unroll
    for (int i = 0; i < 12; ++i)
        outp[(size_t)(ob + i) * HW + l] = acc[i];
}

// ---------------- fused t + aggregation ----------------
// 784 blocks x 512 thr; block = 32 px. Phase 1: 16-way (wave x r-half)
// split of the 800-tap reduction. Phase 2: (g = wave, s-half, px).
__global__ __launch_bounds__(512) void kmain(
    const float* __restrict__ xcat,
    const float* __restrict__ s1, const float* __restrict__ sh1,
    const float* __restrict__ wc1t, const float* __restrict__ b2f,
    const float* __restrict__ wcw2, const float* __restrict__ bcw2,
    float* __restrict__ out)
{
    __shared__ float red[16][8][32];
    __shared__ float tl[8][32];

    const int tid = threadIdx.x;
    const int w   = tid >> 6;
    const int l   = tid & 63;
    const int px  = l & 31;
    const int rh  = l >> 5;
    const int b   = blockIdx.x / 98;
    const int nb  = (blockIdx.x % 98) * 32;
    const int n   = nb + px;
    const int y   = n / HH;
    const int xx  = n - y * HH;

    const float* x1 = xcat + (size_t)b * MOUT * HW;
    const float* x2 = x1 + 16 * HW;
    const int rb = rh * 8;

    float acc[8];
#pragma unroll
    for (int g = 0; g < 8; ++g) acc[g] = 0.f;

    const int u0 = (50 * w) >> 3;
    const int u1 = (50 * (w + 1)) >> 3;

#pragma unroll 1
    for (int u = u0; u < u1; ++u) {
        if (u == 0) {
#pragma unroll
            for (int rr = 0; rr < 8; ++rr) {
                int r = rb + rr;
                float v = x1[r * HW + n];
                v = fmaxf(fmaf(v, s1[r], sh1[r]), 0.f);
                const float4* wq = (const float4*)(wc1t + r * 8);
                float4 A = wq[0], Bv = wq[1];
                acc[0] = fmaf(v, A.x, acc[0]);  acc[1] = fmaf(v, A.y, acc[1]);
                acc[2] = fmaf(v, A.z, acc[2]);  acc[3] = fmaf(v, A.w, acc[3]);
                acc[4] = fmaf(v, Bv.x, acc[4]); acc[5] = fmaf(v, Bv.y, acc[5]);
                acc[6] = fmaf(v, Bv.z, acc[6]); acc[7] = fmaf(v, Bv.w, acc[7]);
            }
        } else {
            const int kk = __builtin_amdgcn_readfirstlane(u - 1);
            const int i  = kk / 7;
            const int jj = kk - i * 7;
            int p = y + 2 * i - 6;
            int q = xx + 2 * jj - 6;
            bool z = (p < -2) | (p > 57) | (q < -2) | (q > 57);
            int off = refl(p) * HH + refl(q);
#pragma unroll
            for (int rr = 0; rr < 8; ++rr) {
                int r = rb + rr;
                int j = 16 + r * KK + kk;
                float v = z ? 0.f : x2[(size_t)r * HW + off];
                v = fmaxf(fmaf(v, s1[j], sh1[j]), 0.f);
                const float4* wq = (const float4*)(wc1t + j * 8);
                float4 A = wq[0], Bv = wq[1];
                acc[0] = fmaf(v, A.x, acc[0]);  acc[1] = fmaf(v, A.y, acc[1]);
                acc[2] = fmaf(v, A.z, acc[2]);  acc[3] = fmaf(v, A.w, acc[3]);
                acc[4] = fmaf(v, Bv.x, acc[4]); acc[5] = fmaf(v, Bv.y, acc[5]);
                acc[6] = fmaf(v, Bv.z, acc[6]); acc[7] = fmaf(v, Bv.w, acc[7]);
            }
        }
    }

#pragma unroll
    for (int g = 0; g < 8; ++g) red[w * 2 + rh][g][px] = acc[g];
    __syncthreads();

    if (tid < 256) {
        int g = tid >> 5, p2 = tid & 31;
        float s = b2f[g];
#pragma unroll
        for (int sl = 0; sl < 16; ++sl) s += red[sl][g][p2];
        tl[g][p2] = fmaxf(s, 0.f);
    }
    __syncthreads();

    // ---- phase 2: aggregation. thread = (g=w, s-half=rh, px) ----
    const int g  = __builtin_amdgcn_readfirstlane(w);
    float t[8];
#pragma unroll
    for (int e = 0; e < 8; ++e) t[e] = tl[e][px];

    const float* x3   = xcat + ((size_t)b * MOUT + 32 + g * 8 + rh * 4) * HW;
    const float* wrow = wcw2 + (size_t)g * KK * 8;   // wave-uniform -> s_load
    const float* brow = bcw2 + (size_t)g * KK;

    float a2[4] = {0.f, 0.f, 0.f, 0.f};

#pragma unroll 1
    for (int i = 0; i < 7; ++i) {
        int p  = y + 2 * i - 6;
        int py = refl(p);
#pragma unroll
        for (int jj = 0; jj < 7; ++jj) {
            int q  = xx + 2 * jj - 6;
            int qx = refl(q);
            int off = py * HH + qx;
            int k   = i * 7 + jj;
            float wvv = brow[k];
            const float* wr = wrow + k * 8;
#pragma unroll
            for (int e = 0; e < 8; ++e) wvv = fmaf(t[e], wr[e], wvv);
#pragma unroll
            for (int s = 0; s < 4; ++s)
                a2[s] = fmaf(x3[(size_t)s * HW + off], wvv, a2[s]);
        }
    }

    float* op = out + ((size_t)b * 64 + g * 8 + rh * 4) * HW + n;
#pragma unroll
    for (int s = 0; s < 4; ++s) op[(size_t)s * HW] = a2[s];
}

extern "C" void kernel_launch(void* const* d_in, const int* in_sizes, int n_in,
                              void* d_out, int out_size, void* d_ws, size_t ws_size,
                              hipStream_t stream) {
    const float* x    = (const float*)d_in[0];
    const float* w1   = (const float*)d_in[1];
    const float* b1   = (const float*)d_in[2];
    const float* w2   = (const float*)d_in[3];
    const float* b2   = (const float*)d_in[4];
    const float* w3   = (const float*)d_in[5];
    const float* b3   = (const float*)d_in[6];
    const float* bn1g = (const float*)d_in[7];
    const float* bn1b = (const float*)d_in[8];
    const float* bn1m = (const float*)d_in[9];
    const float* bn1v = (const float*)d_in[10];
    const float* wcw1 = (const float*)d_in[11];
    const float* bn2g = (const float*)d_in[12];
    const float* bn2b = (const float*)d_in[13];
    const float* bn2m = (const float*)d_in[14];
    const float* bn2v = (const float*)d_in[15];
    const float* wcw2 = (const float*)d_in[16];
    const float* bcw2 = (const float*)d_in[17];

    float* ws = (float*)d_ws;

    kprep<<<125, 256, 0, stream>>>(w1, b1, w2, b2, w3, b3,
                                   bn1g, bn1b, bn1m, bn1v, wcw1,
                                   bn2g, bn2b, bn2m, bn2v, ws);
    kconv<<<392, 512, 0, stream>>>(x, ws + OFF_WT, ws + OFF_BCAT,
                                   ws + OFF_XCAT);
    kmain<<<784, 512, 0, stream>>>(ws + OFF_XCAT, ws + OFF_S1, ws + OFF_SH1,
                                   ws + OFF_WC1T, ws + OFF_B2F, wcw2, bcw2,
                                   (float*)d_out);
}

// Round 5
// 77.779 us; speedup vs baseline: 1.4490x; 1.2339x over previous
//
#include <hip/hip_runtime.h>
#include <hip/hip_bf16.h>

#define HW    3136
#define HH    56
#define NCIN  256
#define KK    49
#define PH    68
#define PP    (PH*PH)   // 4624

// ---------------- ws layout (in floats) ----------------
#define OFF_WT    0          // [256][96]  transposed concat weights
#define OFF_BCAT  24576      // [96]
#define OFF_SSH   24672      // [800][2]   (bn1 scale, shift) interleaved
#define OFF_WC1T  26272      // [800][8]   bn2-folded transposed wcw1
#define OFF_B2F   32672      // [8]
#define OFF_X1    32768      // [8][16][3136]
#define OFF_X2P   434176     // [8][16][4624]  reflect2+zero4 padded
#define OFF_X3P   1026048    // [8][64][4624]  reflect6 padded
#define OFF_TB    3393536    // [8][8][3136]

// ---------------- precompute / repack / zero x2pad ----------------
__global__ __launch_bounds__(256) void kprep(
    const float* __restrict__ w1, const float* __restrict__ b1,
    const float* __restrict__ w2, const float* __restrict__ b2,
    const float* __restrict__ w3, const float* __restrict__ b3,
    const float* __restrict__ bn1g, const float* __restrict__ bn1b,
    const float* __restrict__ bn1m, const float* __restrict__ bn1v,
    const float* __restrict__ wcw1,
    const float* __restrict__ bn2g, const float* __restrict__ bn2b,
    const float* __restrict__ bn2m, const float* __restrict__ bn2v,
    float* __restrict__ ws)
{
    int idx = blockIdx.x * 256 + threadIdx.x;
    if (idx < 24576) {                    // wT[c][o] = W[o][c]
        int o = idx >> 8, c = idx & 255;
        float v = (o < 16) ? w1[o * 256 + c]
                : (o < 32) ? w2[(o - 16) * 256 + c]
                           : w3[(o - 32) * 256 + c];
        ws[OFF_WT + c * 96 + o] = v;
    }
    int i2 = idx - 24576;                 // bcat [96]
    if (i2 >= 0 && i2 < 96) {
        float v = (i2 < 16) ? b1[i2] : (i2 < 32) ? b2[i2 - 16] : b3[i2 - 32];
        ws[OFF_BCAT + i2] = v;
    }
    int i3 = idx - 24672;                 // ssh [800][2]
    if (i3 >= 0 && i3 < 800) {
        float s = bn1g[i3] / sqrtf(bn1v[i3] + 1e-5f);
        ws[OFF_SSH + 2 * i3]     = s;
        ws[OFF_SSH + 2 * i3 + 1] = bn1b[i3] - bn1m[i3] * s;
    }
    int i4 = idx - 25472;                 // wc1t [800][8]
    if (i4 >= 0 && i4 < 6400) {
        int j = i4 >> 3, g = i4 & 7;
        float s2 = bn2g[g] / sqrtf(bn2v[g] + 1e-5f);
        ws[OFF_WC1T + i4] = wcw1[g * 800 + j] * s2;
    }
    int i5 = idx - 31872;                 // b2f [8]
    if (i5 >= 0 && i5 < 8) {
        float s2 = bn2g[i5] / sqrtf(bn2v[i5] + 1e-5f);
        ws[OFF_B2F + i5] = bn2b[i5] - bn2m[i5] * s2;
    }
    int i6 = idx - 31880;                 // zero whole x2pad (interior rewritten by kconv)
    if (i6 >= 0 && i6 < 8 * 16 * PP) {
        ws[OFF_X2P + i6] = 0.f;
    }
}

// ---------------- fused 1x1 convs -> x1 / x2pad / x3pad ----------------
// 512 thr = 8 waves; block = 64 px; wave w owns out-ch [12w,12w+12).
// Weights via wave-uniform pointer -> scalar s_loads. Mirror stores fill
// the reflect bands of the padded buffers.
__global__ __launch_bounds__(512) void kconv(
    const float* __restrict__ x, const float* __restrict__ wT,
    const float* __restrict__ bcat, float* __restrict__ x1out,
    float* __restrict__ x2pad, float* __restrict__ x3pad)
{
    __shared__ float xl[64][64];
    const int tid = threadIdx.x;
    const int l   = tid & 63;
    const int wv  = __builtin_amdgcn_readfirstlane(tid >> 6);
    const int b   = blockIdx.x / 49;
    const int hw0 = (blockIdx.x % 49) * 64;
    const int ob  = wv * 12;

    float acc[12];
    const float* bc = bcat + ob;
#pragma unroll
    for (int i = 0; i < 12; ++i) acc[i] = bc[i];

    const float* xb = x + (size_t)b * NCIN * HW + hw0;

    for (int cc = 0; cc < 4; ++cc) {
        __syncthreads();
#pragma unroll
        for (int i = 0; i < 8; ++i)
            xl[i * 8 + wv][l] = xb[(size_t)(cc * 64 + i * 8 + wv) * HW + l];
        __syncthreads();

        const float* wp = wT + (cc * 64) * 96 + ob;
#pragma unroll 4
        for (int k = 0; k < 64; ++k) {
            float xv = xl[k][l];
            const float4* wq = (const float4*)(wp + k * 96);
            float4 A = wq[0], B = wq[1], C = wq[2];
            acc[0]  = fmaf(xv, A.x, acc[0]);  acc[1]  = fmaf(xv, A.y, acc[1]);
            acc[2]  = fmaf(xv, A.z, acc[2]);  acc[3]  = fmaf(xv, A.w, acc[3]);
            acc[4]  = fmaf(xv, B.x, acc[4]);  acc[5]  = fmaf(xv, B.y, acc[5]);
            acc[6]  = fmaf(xv, B.z, acc[6]);  acc[7]  = fmaf(xv, B.w, acc[7]);
            acc[8]  = fmaf(xv, C.x, acc[8]);  acc[9]  = fmaf(xv, C.y, acc[9]);
            acc[10] = fmaf(xv, C.z, acc[10]); acc[11] = fmaf(xv, C.w, acc[11]);
        }
    }

    // ---- stores with padded-buffer mirrors ----
    const int n  = hw0 + l;
    const int y  = n / HH;
    const int xx = n - y * HH;
    const int p0 = y + 6, q0 = xx + 6;
    // x3 (reflect 6): mirror rows/cols
    const int yr3 = (y >= 1 && y <= 6) ? 6 - y : ((y >= 49 && y <= 54) ? 116 - y : -1);
    const int xr3 = (xx >= 1 && xx <= 6) ? 6 - xx : ((xx >= 49 && xx <= 54) ? 116 - xx : -1);
    // x2 (reflect 2 then zero 4): only y in {1,2,53,54} mirror
    const int yr2 = (y == 1 || y == 2) ? 6 - y : ((y == 53 || y == 54) ? 116 - y : -1);
    const int xr2 = (xx == 1 || xx == 2) ? 6 - xx : ((xx == 53 || xx == 54) ? 116 - xx : -1);

#pragma unroll
    for (int i = 0; i < 12; ++i) {
        const int ch = ob + i;             // wave-uniform
        const float v = acc[i];
        if (ch < 16) {
            x1out[((size_t)b * 16 + ch) * HW + n] = v;
        } else if (ch < 32) {
            float* pl = x2pad + ((size_t)b * 16 + (ch - 16)) * PP;
            pl[p0 * PH + q0] = v;
            if (yr2 >= 0)              pl[yr2 * PH + q0]  = v;
            if (xr2 >= 0)              pl[p0 * PH + xr2]  = v;
            if (yr2 >= 0 && xr2 >= 0)  pl[yr2 * PH + xr2] = v;
        } else {
            float* pl = x3pad + ((size_t)b * 64 + (ch - 32)) * PP;
            pl[p0 * PH + q0] = v;
            if (yr3 >= 0)              pl[yr3 * PH + q0]  = v;
            if (xr3 >= 0)              pl[p0 * PH + xr3]  = v;
            if (yr3 >= 0 && xr3 >= 0)  pl[yr3 * PH + xr3] = v;
        }
    }
}

// ---------------- t: per-pixel 8-dim bottleneck ----------------
// 512 thr = 8 waves; block = 64 px. Wave w handles tap-units
// [(50w)>>3,(50(w+1))>>3); padded x2 -> branch-free const-offset loads.
__global__ __launch_bounds__(512) void kt(
    const float* __restrict__ x1, const float* __restrict__ x2pad,
    const float* __restrict__ ssh, const float* __restrict__ wc1t,
    const float* __restrict__ b2f, float* __restrict__ tbuf)
{
    __shared__ float red[8][8][64];
    const int tid = threadIdx.x;
    const int w   = __builtin_amdgcn_readfirstlane(tid >> 6);
    const int l   = tid & 63;
    const int b   = blockIdx.x / 49;
    const int nb  = (blockIdx.x % 49) * 64;
    const int n   = nb + l;
    const int y   = n / HH;
    const int xx  = n - y * HH;
    const int pbase = y * PH + xx;

    const float* x1b = x1 + (size_t)b * 16 * HW + n;
    const float* x2b = x2pad + (size_t)b * 16 * PP + pbase;

    float acc[8];
#pragma unroll
    for (int g = 0; g < 8; ++g) acc[g] = 0.f;

    const int u0 = (50 * w) >> 3;
    const int u1 = (50 * (w + 1)) >> 3;

#pragma unroll 2
    for (int u = u0; u < u1; ++u) {
        if (u == 0) {
#pragma unroll
            for (int r = 0; r < 16; ++r) {
                float v = x1b[(size_t)r * HW];
                float2 ss = *(const float2*)(ssh + 2 * r);
                v = fmaxf(fmaf(v, ss.x, ss.y), 0.f);
                const float4* wq = (const float4*)(wc1t + r * 8);
                float4 A = wq[0], Bv = wq[1];
                acc[0] = fmaf(v, A.x, acc[0]);  acc[1] = fmaf(v, A.y, acc[1]);
                acc[2] = fmaf(v, A.z, acc[2]);  acc[3] = fmaf(v, A.w, acc[3]);
                acc[4] = fmaf(v, Bv.x, acc[4]); acc[5] = fmaf(v, Bv.y, acc[5]);
                acc[6] = fmaf(v, Bv.z, acc[6]); acc[7] = fmaf(v, Bv.w, acc[7]);
            }
        } else {
            const int kk = __builtin_amdgcn_readfirstlane(u - 1);
            const int i  = kk / 7;
            const int jj = kk - i * 7;
            const float* xp = x2b + i * (2 * PH) + jj * 2;
#pragma unroll
            for (int r = 0; r < 16; ++r) {
                const int j = 16 + r * KK + kk;   // wave-uniform -> s_load
                float v = xp[(size_t)r * PP];
                float2 ss = *(const float2*)(ssh + 2 * j);
                v = fmaxf(fmaf(v, ss.x, ss.y), 0.f);
                const float4* wq = (const float4*)(wc1t + j * 8);
                float4 A = wq[0], Bv = wq[1];
                acc[0] = fmaf(v, A.x, acc[0]);  acc[1] = fmaf(v, A.y, acc[1]);
                acc[2] = fmaf(v, A.z, acc[2]);  acc[3] = fmaf(v, A.w, acc[3]);
                acc[4] = fmaf(v, Bv.x, acc[4]); acc[5] = fmaf(v, Bv.y, acc[5]);
                acc[6] = fmaf(v, Bv.z, acc[6]); acc[7] = fmaf(v, Bv.w, acc[7]);
            }
        }
    }

#pragma unroll
    for (int g = 0; g < 8; ++g) red[w][g][l] = acc[g];
    __syncthreads();

    {   // 512 threads <-> (g, px)
        const int g  = tid >> 6;
        const int px = tid & 63;
        float s = b2f[g];
#pragma unroll
        for (int ww = 0; ww < 8; ++ww) s += red[ww][g][px];
        tbuf[((size_t)b * 8 + g) * HW + nb + px] = fmaxf(s, 0.f);
    }
}

// ---------------- aggregation (padded x3, px-pair float2) ----------------
// 512 thr = 8 waves; wave = g; lane = (s-half, px-pair); block = 64 px.
__global__ __launch_bounds__(512) void kagg(
    const float* __restrict__ x3pad, const float* __restrict__ tbuf,
    const float* __restrict__ wcw2, const float* __restrict__ bcw2,
    float* __restrict__ out)
{
    const int tid  = threadIdx.x;
    const int g    = __builtin_amdgcn_readfirstlane(tid >> 6);
    const int lane = tid & 63;
    const int sh   = lane >> 5;
    const int pp   = lane & 31;
    const int b    = blockIdx.x / 49;
    const int nb   = (blockIdx.x % 49) * 64;
    const int n0   = nb + pp * 2;          // even -> pair never straddles a row
    const int y    = n0 / HH;
    const int xx   = n0 - y * HH;
    const int pbase = y * PH + xx;

    float t0[8], t1[8];
#pragma unroll
    for (int e = 0; e < 8; ++e) {
        float2 tv = *(const float2*)(tbuf + ((size_t)b * 8 + e) * HW + n0);
        t0[e] = tv.x; t1[e] = tv.y;
    }

    float2 acc[4];
#pragma unroll
    for (int s = 0; s < 4; ++s) acc[s] = make_float2(0.f, 0.f);

    const float* x3b = x3pad + ((size_t)b * 64 + g * 8 + sh * 4) * PP + pbase;
    const float* wr  = wcw2 + (size_t)g * KK * 8;   // wave-uniform -> s_load
    const float* br  = bcw2 + (size_t)g * KK;

#pragma unroll 1
    for (int i = 0; i < 7; ++i) {
        const float* xrow = x3b + i * (2 * PH);
#pragma unroll
        for (int jj = 0; jj < 7; ++jj) {
            const int k = i * 7 + jj;
            float w0 = br[k], w1 = w0;
            const float* wk = wr + k * 8;
#pragma unroll
            for (int e = 0; e < 8; ++e) {
                float we = wk[e];
                w0 = fmaf(t0[e], we, w0);
                w1 = fmaf(t1[e], we, w1);
            }
#pragma unroll
            for (int s = 0; s < 4; ++s) {
                float2 xv = *(const float2*)(xrow + (size_t)s * PP + jj * 2);
                acc[s].x = fmaf(xv.x, w0, acc[s].x);
                acc[s].y = fmaf(xv.y, w1, acc[s].y);
            }
        }
    }

    float* op = out + ((size_t)b * 64 + g * 8 + sh * 4) * HW + n0;
#pragma unroll
    for (int s = 0; s < 4; ++s)
        *(float2*)(op + (size_t)s * HW) = acc[s];
}

extern "C" void kernel_launch(void* const* d_in, const int* in_sizes, int n_in,
                              void* d_out, int out_size, void* d_ws, size_t ws_size,
                              hipStream_t stream) {
    const float* x    = (const float*)d_in[0];
    const float* w1   = (const float*)d_in[1];
    const float* b1   = (const float*)d_in[2];
    const float* w2   = (const float*)d_in[3];
    const float* b2   = (const float*)d_in[4];
    const float* w3   = (const float*)d_in[5];
    const float* b3   = (const float*)d_in[6];
    const float* bn1g = (const float*)d_in[7];
    const float* bn1b = (const float*)d_in[8];
    const float* bn1m = (const float*)d_in[9];
    const float* bn1v = (const float*)d_in[10];
    const float* wcw1 = (const float*)d_in[11];
    const float* bn2g = (const float*)d_in[12];
    const float* bn2b = (const float*)d_in[13];
    const float* bn2m = (const float*)d_in[14];
    const float* bn2v = (const float*)d_in[15];
    const float* wcw2 = (const float*)d_in[16];
    const float* bcw2 = (const float*)d_in[17];

    float* ws = (float*)d_ws;

    kprep<<<2437, 256, 0, stream>>>(w1, b1, w2, b2, w3, b3,
                                    bn1g, bn1b, bn1m, bn1v, wcw1,
                                    bn2g, bn2b, bn2m, bn2v, ws);
    kconv<<<392, 512, 0, stream>>>(x, ws + OFF_WT, ws + OFF_BCAT,
                                   ws + OFF_X1, ws + OFF_X2P, ws + OFF_X3P);
    kt<<<392, 512, 0, stream>>>(ws + OFF_X1, ws + OFF_X2P,
                                ws + OFF_SSH, ws + OFF_WC1T, ws + OFF_B2F,
                                ws + OFF_TB);
    kagg<<<392, 512, 0, stream>>>(ws + OFF_X3P, ws + OFF_TB, wcw2, bcw2,
                                  (float*)d_out);
}